// Round 9
// baseline (491.474 us; speedup 1.0000x reference)
//
#include <hip/hip_runtime.h>
#include <stdint.h>

#define B_DIM 8
#define T_DIM 4096
#define K_DIM 1024
#define H_DIM 1024
#define M_DIM (B_DIM * T_DIM)      // 32768
#define CHUNK 64
#define NCHUNK (T_DIM / CHUNK)     // 64

typedef __attribute__((ext_vector_type(8))) short s16x8;
typedef __attribute__((ext_vector_type(4))) float f32x4;

__device__ __forceinline__ unsigned short f2b(float f) {
    union { float f; uint32_t u; } c; c.f = f;
    uint32_t r = (c.u + 0x7fffu + ((c.u >> 16) & 1u)) >> 16;
    return (unsigned short)r;
}
__device__ __forceinline__ float b2f(unsigned short u) {
    union { uint32_t u; float f; } c; c.u = ((uint32_t)u) << 16;
    return c.f;
}

// async global->LDS, 16B per lane. LDS dest = wave-uniform base + lane*16.
__device__ __forceinline__ void gload_lds16(const unsigned short* g,
                                            unsigned short* l) {
    __builtin_amdgcn_global_load_lds(
        (__attribute__((address_space(1))) void*)g,
        (__attribute__((address_space(3))) void*)l, 16, 0, 0);
}

// ---------------- conversion kernels ----------------

__global__ void cvt_f32_bf16(const float* __restrict__ src,
                             unsigned short* __restrict__ dst, int n4) {
    int stride = gridDim.x * blockDim.x;
    for (int i = blockIdx.x * blockDim.x + threadIdx.x; i < n4; i += stride) {
        float4 v = ((const float4*)src)[i];
        ushort4 o;
        o.x = f2b(v.x); o.y = f2b(v.y); o.z = f2b(v.z); o.w = f2b(v.w);
        ((ushort4*)dst)[i] = o;
    }
}

// W'[2c+0][k] = W_hg[c][k] (hidden row), W'[2c+1][k] = W_hg[H+c][k] (gate row)
__global__ void prep_whg(const float* __restrict__ W,
                         unsigned short* __restrict__ Wp) {
    int i = blockIdx.x * blockDim.x + threadIdx.x;
    int total = 2 * H_DIM * K_DIM / 4;
    if (i >= total) return;
    int e = i * 4;
    int n = e >> 10;          // K = 1024
    int k = e & 1023;
    int src = (n & 1) ? (H_DIM + (n >> 1)) : (n >> 1);
    float4 v = *(const float4*)&W[(size_t)src * K_DIM + k];
    ushort4 o;
    o.x = f2b(v.x); o.y = f2b(v.y); o.z = f2b(v.z); o.w = f2b(v.w);
    *(ushort4*)&Wp[(size_t)n * K_DIM + k] = o;
}

// ---------------- 128x128 m97-structure bf16 MFMA GEMM ----------------
// C[m,n] = sum_k A[m,k] * Bm[n,k].  BM=BN=128, BK=64, 4 waves (2Mx2N),
// 32KB single-buffered LDS -> 3-4 blocks/CU; cross-block wave overlap hides
// the per-K-step stage drain (m97: 874-912 TF with this exact pattern).
// NO inline-asm waitcnts, NO setprio: compiler-scheduled (m141/m190 lessons).
// LDS unit layout: 16 blocks of 1KB = [rowblk(8) x khalf(2)][kq(4)][row(16)][8]
//   -> gload_lds writes linear; wave's fragment ds_read_b128 is one contiguous
//      1KB block = 2 lanes/bank = conflict-free (R6/R8-verified numerics).
// EPI==0: f32 store. EPI==1: fused minGRU gating -> packed u32
//         Sab[row][ch] = {lo: bf16(1-g), hi: bf16(g*hidden)}.

template <int EPI>
__global__ __launch_bounds__(256, 3) void gemm128(
    const unsigned short* __restrict__ A,
    const unsigned short* __restrict__ Bm,
    float* __restrict__ C,
    uint32_t* __restrict__ Sab,
    int N) {
    __shared__ unsigned short As[128 * 64];
    __shared__ unsigned short Bs[128 * 64];
    const int K = K_DIM;
    const int KT = K / 64;   // 16

    // T1: bijective XCD swizzle (nwg % 8 == 0 for both GEMMs here)
    const int gx = gridDim.x;
    const int nwg = gx * gridDim.y;
    const int orig = blockIdx.y * gx + blockIdx.x;
    const int cpx = nwg >> 3;
    const int wg = (orig & 7) * cpx + (orig >> 3);
    const int m0 = (wg / gx) * 128;
    const int n0 = (wg % gx) * 128;

    const int t = threadIdx.x;
    const int lane = t & 63;
    const int w = t >> 6;               // 0..3
    const int wm = w >> 1, wn = w & 1;  // 2 x 2 wave grid

    // staging lane geometry: row (lane&15), k-quarter (lane>>4)
    const int srow = lane & 15;
    const int sq   = lane >> 4;

    // fragment-read lane geometry (same (l15,rq) rule as all passing rounds)
    const int l15 = lane & 15;
    const int rq  = lane >> 4;          // 0..3

    f32x4 acc[4][4];
#pragma unroll
    for (int m = 0; m < 4; m++)
#pragma unroll
        for (int n = 0; n < 4; n++) acc[m][n] = (f32x4){0.f, 0.f, 0.f, 0.f};

    for (int kt = 0; kt < KT; ++kt) {
        // ---- stage tile kt (8 gload_lds; block bi = j*4+w is wave-uniform)
        const int gkb = kt * 64;
#pragma unroll
        for (int j = 0; j < 4; j++) {
            const int bi = j * 4 + w;            // 0..15
            const int mi = bi >> 1, ks = bi & 1; // rowblk, k-half
            gload_lds16(&A[(size_t)(m0 + mi * 16 + srow) * K + gkb + ks * 32 + sq * 8],
                        &As[bi * 512]);
            gload_lds16(&Bm[(size_t)(n0 + mi * 16 + srow) * K + gkb + ks * 32 + sq * 8],
                        &Bs[bi * 512]);
        }
        __syncthreads();   // compiler emits vmcnt(0) drain; other blocks cover it

        // ---- compute tile kt: 16 ds_read_b128 + 32 MFMA (compiler-scheduled)
#pragma unroll
        for (int ks = 0; ks < 2; ++ks) {
            s16x8 af[4], bf[4];
#pragma unroll
            for (int m = 0; m < 4; m++)
                af[m] = *(const s16x8*)&As[((wm * 4 + m) * 2 + ks) * 512 + rq * 128 + l15 * 8];
#pragma unroll
            for (int n = 0; n < 4; n++)
                bf[n] = *(const s16x8*)&Bs[((wn * 4 + n) * 2 + ks) * 512 + rq * 128 + l15 * 8];
#pragma unroll
            for (int m = 0; m < 4; m++)
#pragma unroll
                for (int n = 0; n < 4; n++)
                    acc[m][n] = __builtin_amdgcn_mfma_f32_16x16x32_bf16(
                        af[m], bf[n], acc[m][n], 0, 0, 0);
        }
        __syncthreads();   // reads done before next stage overwrites LDS
    }

    // ---- epilogue
    const int lr4 = rq * 4;
#pragma unroll
    for (int m = 0; m < 4; m++) {
#pragma unroll
        for (int n = 0; n < 4; n++) {
#pragma unroll
            for (int r = 0; r < 4; r++) {
                const int row = m0 + wm * 64 + m * 16 + lr4 + r;
                const int col = n0 + wn * 64 + n * 16 + l15;
                float v = acc[m][n][r];
                if (EPI == 0) {
                    C[(size_t)row * N + col] = v;
                } else {
                    float o = __shfl_xor(v, 1);   // all lanes execute
                    if ((lane & 1) == 0) {
                        // even lane: v = hidden, o = gate logit -> pack both
                        float g = 1.f / (1.f + __expf(-o));
                        uint32_t pk = (uint32_t)f2b(1.f - g) |
                                      ((uint32_t)f2b(g * v) << 16);
                        Sab[(size_t)row * H_DIM + (col >> 1)] = pk;
                    }
                }
            }
        }
    }
}

// ---------------- chunked scan (3-pass, packed coefficients) ----------------
// Element combine (matches reference): carry (A,Bv); element (a,b,r):
//   r>0 : (A,Bv) = (a, b)      else : (A,Bv) = (a*A, a*Bv + b)

__global__ __launch_bounds__(256) void scan_chunks(
    const uint32_t* __restrict__ Sab, const float* __restrict__ is_init,
    float* __restrict__ CA, float* __restrict__ CB, float* __restrict__ CR) {
    int idx = blockIdx.x * 256 + threadIdx.x;      // b*65536 + chunk*1024 + ch
    int ch = idx & (H_DIM - 1);
    int chunk = (idx >> 10) & (NCHUNK - 1);
    int b = idx >> 16;
    int t0 = chunk * CHUNK;
    size_t base = ((size_t)b * T_DIM + t0) * H_DIM + ch;
    const float* ii = is_init + (size_t)b * T_DIM + t0;
    float A = 1.f, Bv = 0.f;
    int rf = 0;
    for (int i = 0; i < CHUNK; i++) {
        uint32_t d = Sab[base + (size_t)i * H_DIM];
        float a = b2f((unsigned short)(d & 0xffffu));
        float bb = b2f((unsigned short)(d >> 16));
        bool rst = ii[i] > 0.f;
        A = rst ? a : a * A;
        Bv = rst ? bb : fmaf(a, Bv, bb);
        rf |= (int)rst;
    }
    size_t o = ((size_t)b * NCHUNK + chunk) * H_DIM + ch;
    CA[o] = A;
    CB[o] = Bv;
    if (ch == 0) CR[b * NCHUNK + chunk] = (float)rf;
}

__global__ void scan_tops(const float* __restrict__ CA, const float* __restrict__ CB,
                          const float* __restrict__ CR,
                          float* __restrict__ PA, float* __restrict__ PB) {
    int idx = blockIdx.x * blockDim.x + threadIdx.x;   // 0 .. B*H-1
    if (idx >= B_DIM * H_DIM) return;
    int ch = idx & (H_DIM - 1);
    int b = idx >> 10;
    float A = 1.f, Bv = 0.f;
    for (int c = 0; c < NCHUNK; c++) {
        size_t o = ((size_t)b * NCHUNK + c) * H_DIM + ch;
        PA[o] = A;            // exclusive prefix
        PB[o] = Bv;
        float a = CA[o], bb = CB[o];
        bool rst = CR[b * NCHUNK + c] > 0.f;
        float nA = rst ? a : a * A;
        float nB = rst ? bb : fmaf(a, Bv, bb);
        A = nA; Bv = nB;
    }
}

__global__ __launch_bounds__(256) void scan_apply(
    const uint32_t* __restrict__ Sab, const float* __restrict__ is_init,
    const float* __restrict__ PA, const float* __restrict__ PB,
    const float* __restrict__ h0,
    unsigned short* __restrict__ hb, float* __restrict__ hn) {
    int idx = blockIdx.x * 256 + threadIdx.x;
    int ch = idx & (H_DIM - 1);
    int chunk = (idx >> 10) & (NCHUNK - 1);
    int b = idx >> 16;
    int t0 = chunk * CHUNK;
    size_t base = ((size_t)b * T_DIM + t0) * H_DIM + ch;
    const float* ii = is_init + (size_t)b * T_DIM + t0;
    size_t po = ((size_t)b * NCHUNK + chunk) * H_DIM + ch;
    float A = PA[po], Bv = PB[po];
    float h0v = h0[b * H_DIM + ch];
    float h = 0.f;
    for (int i = 0; i < CHUNK; i++) {
        uint32_t d = Sab[base + (size_t)i * H_DIM];
        float a = b2f((unsigned short)(d & 0xffffu));
        float bb = b2f((unsigned short)(d >> 16));
        bool rst = ii[i] > 0.f;
        A = rst ? a : a * A;
        Bv = rst ? bb : fmaf(a, Bv, bb);
        h = fmaf(A, h0v, Bv);
        hb[base + (size_t)i * H_DIM] = f2b(h);
    }
    if (chunk == NCHUNK - 1) hn[b * H_DIM + ch] = h;
}

// ---------------- launcher ----------------

extern "C" void kernel_launch(void* const* d_in, const int* in_sizes, int n_in,
                              void* d_out, int out_size, void* d_ws, size_t ws_size,
                              hipStream_t stream) {
    const float* x       = (const float*)d_in[0];
    const float* W_hg    = (const float*)d_in[1];
    const float* W_out   = (const float*)d_in[2];
    const float* is_init = (const float*)d_in[3];
    const float* h0      = (const float*)d_in[4];
    float* out = (float*)d_out;
    float* hn  = out + (size_t)M_DIM * H_DIM;

    char* ws = (char*)d_ws;
    size_t off = 0;
    auto alloc = [&](size_t bytes) {
        void* p = ws + off;
        off += (bytes + 255) & ~(size_t)255;
        return p;
    };
    unsigned short* xb  = (unsigned short*)alloc((size_t)M_DIM * K_DIM * 2); // reused as hb
    unsigned short* Wp  = (unsigned short*)alloc((size_t)2 * H_DIM * K_DIM * 2);
    unsigned short* Wob = (unsigned short*)alloc((size_t)H_DIM * K_DIM * 2);
    uint32_t* Sab = (uint32_t*)alloc((size_t)M_DIM * H_DIM * 4);
    float* CA = (float*)alloc((size_t)B_DIM * NCHUNK * H_DIM * 4);
    float* CB = (float*)alloc((size_t)B_DIM * NCHUNK * H_DIM * 4);
    float* CR = (float*)alloc((size_t)B_DIM * NCHUNK * 4);
    float* PA = (float*)alloc((size_t)B_DIM * NCHUNK * H_DIM * 4);
    float* PB = (float*)alloc((size_t)B_DIM * NCHUNK * H_DIM * 4);
    unsigned short* hb = xb;   // alias: x_bf16 dead after GEMM1

    // 1) conversions
    cvt_f32_bf16<<<2048, 256, 0, stream>>>(x, xb, M_DIM * K_DIM / 4);
    prep_whg<<<(2 * H_DIM * K_DIM / 4 + 255) / 256, 256, 0, stream>>>(W_hg, Wp);
    cvt_f32_bf16<<<1024, 256, 0, stream>>>(W_out, Wob, H_DIM * K_DIM / 4);

    // 2) GEMM1 with fused gating epilogue (N = 2048 interleaved cols)
    gemm128<1><<<dim3(2048 / 128, M_DIM / 128), 256, 0, stream>>>(
        xb, Wp, nullptr, Sab, 2048);

    // 3) 3-pass chunked scan over time (packed coefficients)
    scan_chunks<<<(B_DIM * NCHUNK * H_DIM) / 256, 256, 0, stream>>>(
        Sab, is_init, CA, CB, CR);
    scan_tops<<<(B_DIM * H_DIM + 255) / 256, 256, 0, stream>>>(CA, CB, CR, PA, PB);
    scan_apply<<<(B_DIM * NCHUNK * H_DIM) / 256, 256, 0, stream>>>(
        Sab, is_init, PA, PB, h0, hb, hn);

    // 4) GEMM2: out = h @ W_out^T
    gemm128<0><<<dim3(1024 / 128, M_DIM / 128), 256, 0, stream>>>(
        hb, Wob, out, nullptr, 1024);
}

// Round 10
// 457.293 us; speedup vs baseline: 1.0747x; 1.0747x over previous
//
#include <hip/hip_runtime.h>
#include <stdint.h>

#define B_DIM 8
#define T_DIM 4096
#define K_DIM 1024
#define H_DIM 1024
#define M_DIM (B_DIM * T_DIM)      // 32768
#define CHUNK 64
#define NCHUNK (T_DIM / CHUNK)     // 64

typedef __attribute__((ext_vector_type(8))) short s16x8;
typedef __attribute__((ext_vector_type(4))) float f32x4;

__device__ __forceinline__ unsigned short f2b(float f) {
    union { float f; uint32_t u; } c; c.f = f;
    uint32_t r = (c.u + 0x7fffu + ((c.u >> 16) & 1u)) >> 16;
    return (unsigned short)r;
}
__device__ __forceinline__ float b2f(unsigned short u) {
    union { uint32_t u; float f; } c; c.u = ((uint32_t)u) << 16;
    return c.f;
}

// async global->LDS, 16B per lane. LDS dest = wave-uniform base + lane*16.
__device__ __forceinline__ void gload_lds16(const unsigned short* g,
                                            unsigned short* l) {
    __builtin_amdgcn_global_load_lds(
        (__attribute__((address_space(1))) void*)g,
        (__attribute__((address_space(3))) void*)l, 16, 0, 0);
}

__device__ __forceinline__ void bar() {
    asm volatile("s_barrier" ::: "memory");
}

// ---------------- conversion kernels ----------------

__global__ void cvt_f32_bf16(const float* __restrict__ src,
                             unsigned short* __restrict__ dst, int n4) {
    int stride = gridDim.x * blockDim.x;
    for (int i = blockIdx.x * blockDim.x + threadIdx.x; i < n4; i += stride) {
        float4 v = ((const float4*)src)[i];
        ushort4 o;
        o.x = f2b(v.x); o.y = f2b(v.y); o.z = f2b(v.z); o.w = f2b(v.w);
        ((ushort4*)dst)[i] = o;
    }
}

// W'[2c+0][k] = W_hg[c][k] (hidden row), W'[2c+1][k] = W_hg[H+c][k] (gate row)
__global__ void prep_whg(const float* __restrict__ W,
                         unsigned short* __restrict__ Wp) {
    int i = blockIdx.x * blockDim.x + threadIdx.x;
    int total = 2 * H_DIM * K_DIM / 4;
    if (i >= total) return;
    int e = i * 4;
    int n = e >> 10;          // K = 1024
    int k = e & 1023;
    int src = (n & 1) ? (H_DIM + (n >> 1)) : (n >> 1);
    float4 v = *(const float4*)&W[(size_t)src * K_DIM + k];
    ushort4 o;
    o.x = f2b(v.x); o.y = f2b(v.y); o.z = f2b(v.z); o.w = f2b(v.w);
    *(ushort4*)&Wp[(size_t)n * K_DIM + k] = o;
}

// ------------- 256x256 bf16 MFMA GEMM: R7 skeleton + counted vmcnt ---------
// C[m,n] = sum_k A[m,k] * Bm[n,k].  BM=BN=256, BK=64, 8 waves (2Mx4N).
// LDS: 4-slot ring per matrix; unit = 256 rows x 32 k = 16KB, slot=(2kt+ks)&3
// (R6/R8-verified layout: HW-linear staging, contiguous-1KB wave reads,
// 0 bank conflicts). Per tile: 4 phases {ds_read, 1-unit stage (2 loads),
// bar, 16 MFMA, bar}. vmcnt(4) after MFMA at P2/P4 validates loads issued
// 2-4 phases earlier; queue NEVER drains in the main loop (m218 invariant).
// Stage targets (slots s0^2, s1^2) are disjoint from read slots (s0, s1).
// EPI==0: f32 store. EPI==1: fused minGRU gating -> packed u32
//         Sab[row][ch] = {lo: bf16(1-g), hi: bf16(g*hidden)}.

template <int EPI>
__global__ __launch_bounds__(512, 2) void gemm256(
    const unsigned short* __restrict__ A,
    const unsigned short* __restrict__ Bm,
    float* __restrict__ C,
    uint32_t* __restrict__ Sab,
    int N) {
    __shared__ unsigned short As4[4][256 * 32];
    __shared__ unsigned short Bs4[4][256 * 32];
    const int K = K_DIM;
    const int KT = K / 64;   // 16

    // T1: bijective XCD swizzle (nwg % 8 == 0 for both GEMMs here)
    const int gx = gridDim.x;
    const int nwg = gx * gridDim.y;
    const int orig = blockIdx.y * gx + blockIdx.x;
    const int cpx = nwg >> 3;
    const int wg = (orig & 7) * cpx + (orig >> 3);
    const int m0 = (wg / gx) * 256;
    const int n0 = (wg % gx) * 256;

    const int t = threadIdx.x;
    const int lane = t & 63;
    const int w = t >> 6;               // 0..7
    const int wm = w >> 2, wn = w & 3;  // 2 x 4 wave grid

    // staging lane geometry: row (lane&15), k-quarter (lane>>4)
    const int srow = lane & 15;
    const int sq   = lane >> 4;

    // fragment-read lane geometry
    const int l15 = lane & 15;
    const int rq  = lane >> 4;          // 0..3

    f32x4 acc[8][4];
#pragma unroll
    for (int m = 0; m < 8; m++)
#pragma unroll
        for (int n = 0; n < 4; n++) acc[m][n] = (f32x4){0.f, 0.f, 0.f, 0.f};

    // stage one 16-row x 32-k block (1KB) of unit (kt,ks); j = row-half 0/1
    auto stA = [&](int kt, int ks, int j) {
        const int slot = (2 * kt + ks) & 3;
        const int row = j * 128 + w * 16 + srow;
        const int gk  = kt * 64 + ks * 32 + sq * 8;
        gload_lds16(&A[(size_t)(m0 + row) * K + gk],
                    &As4[slot][(j * 128 + w * 16) * 32]);
    };
    auto stB = [&](int kt, int ks, int j) {
        const int slot = (2 * kt + ks) & 3;
        const int row = j * 128 + w * 16 + srow;
        const int gk  = kt * 64 + ks * 32 + sq * 8;
        gload_lds16(&Bm[(size_t)(n0 + row) * K + gk],
                    &Bs4[slot][(j * 128 + w * 16) * 32]);
    };

    s16x8 af[4], bf[4];

    // fragment reads: unit layout rowblk*512 + kq*128 + row15*8 (elems)
#define LDAX(S, MI) \
    (*(const s16x8*)&As4[S][(wm * 8 + (MI)) * 512 + rq * 128 + l15 * 8])
#define LDBX(S, NI) \
    (*(const s16x8*)&Bs4[S][(wn * 4 + (NI)) * 512 + rq * 128 + l15 * 8])

#define VMW4 asm volatile("s_waitcnt vmcnt(4)" ::: "memory")
#define VMW0 asm volatile("s_waitcnt vmcnt(0)" ::: "memory")
#define NOPX ((void)0)

#define STA(KT_, KS_) do { stA((KT_), (KS_), 0); stA((KT_), (KS_), 1); } while (0)
#define STB(KT_, KS_) do { stB((KT_), (KS_), 0); stB((KT_), (KS_), 1); } while (0)

#define MFMA16(MB) do {                                                     \
    __builtin_amdgcn_s_setprio(1);                                          \
    _Pragma("unroll") for (int m_ = 0; m_ < 4; m_++)                        \
        _Pragma("unroll") for (int n_ = 0; n_ < 4; n_++)                    \
            acc[(MB) + m_][n_] = __builtin_amdgcn_mfma_f32_16x16x32_bf16(   \
                af[m_], bf[n_], acc[(MB) + m_][n_], 0, 0, 0);               \
    __builtin_amdgcn_s_setprio(0);                                          \
} while (0)

    // Tile kt: P1{rd(s0,m0-3)+rd B(s0); stage A-ks0(kt+1)} P2{rd(s0,m4-7);
    // stage B-ks0(kt+1); MFMA; VMW2} P3{rd(s1,m0-3)+B(s1); stage A-ks1(kt+1)}
    // P4{rd(s1,m4-7); stage B-ks1(kt+1); MFMA; VMW4'}
#define TILE(T_, S1, S2, S3, S4, W2, W4) do {                               \
    const int s0_ = (2 * (T_)) & 3, s1_ = (2 * (T_) + 1) & 3;               \
    _Pragma("unroll") for (int m_ = 0; m_ < 4; m_++) af[m_] = LDAX(s0_, m_);\
    _Pragma("unroll") for (int n_ = 0; n_ < 4; n_++) bf[n_] = LDBX(s0_, n_);\
    S1;                                                                     \
    bar(); MFMA16(0); bar();                                                \
    _Pragma("unroll") for (int m_ = 0; m_ < 4; m_++) af[m_] = LDAX(s0_, m_ + 4); \
    S2;                                                                     \
    bar(); MFMA16(4); W2; bar();                                            \
    _Pragma("unroll") for (int m_ = 0; m_ < 4; m_++) af[m_] = LDAX(s1_, m_);\
    _Pragma("unroll") for (int n_ = 0; n_ < 4; n_++) bf[n_] = LDBX(s1_, n_);\
    S3;                                                                     \
    bar(); MFMA16(0); bar();                                                \
    _Pragma("unroll") for (int m_ = 0; m_ < 4; m_++) af[m_] = LDAX(s1_, m_ + 4); \
    S4;                                                                     \
    bar(); MFMA16(4); W4; bar();                                            \
} while (0)

    // prologue: stage all 4 units of tile 0; validate first two (A0k0,B0k0)
    STA(0, 0); STB(0, 0);
    STA(0, 1); STB(0, 1);
    VMW4;
    bar();

    // main loop: stage tile kt+1 one unit per phase; vmcnt(4) twice per tile
    for (int kt = 0; kt < KT - 1; ++kt) {
        TILE(kt, STA(kt + 1, 0), STB(kt + 1, 0),
                 STA(kt + 1, 1), STB(kt + 1, 1), VMW4, VMW4);
    }
    // last tile: no stages; only 4 loads in flight at P2 (2-3 phases old)
    TILE(KT - 1, NOPX, NOPX, NOPX, NOPX, VMW0, NOPX);

    // ---- epilogue
    const int lr4 = rq * 4;
#pragma unroll
    for (int m = 0; m < 8; m++) {
#pragma unroll
        for (int n = 0; n < 4; n++) {
#pragma unroll
            for (int r = 0; r < 4; r++) {
                const int row = m0 + wm * 128 + m * 16 + lr4 + r;
                const int col = n0 + wn * 64 + n * 16 + l15;
                float v = acc[m][n][r];
                if (EPI == 0) {
                    C[(size_t)row * N + col] = v;
                } else {
                    float o = __shfl_xor(v, 1);   // all lanes execute
                    if ((lane & 1) == 0) {
                        // even lane: v = hidden, o = gate logit -> pack both
                        float g = 1.f / (1.f + __expf(-o));
                        uint32_t pk = (uint32_t)f2b(1.f - g) |
                                      ((uint32_t)f2b(g * v) << 16);
                        Sab[(size_t)row * H_DIM + (col >> 1)] = pk;
                    }
                }
            }
        }
    }
#undef LDAX
#undef LDBX
#undef TILE
#undef MFMA16
#undef STA
#undef STB
}

// ---------------- chunked scan (3-pass, packed coefficients) ----------------
// Element combine (matches reference): carry (A,Bv); element (a,b,r):
//   r>0 : (A,Bv) = (a, b)      else : (A,Bv) = (a*A, a*Bv + b)

__global__ __launch_bounds__(256) void scan_chunks(
    const uint32_t* __restrict__ Sab, const float* __restrict__ is_init,
    float* __restrict__ CA, float* __restrict__ CB, float* __restrict__ CR) {
    int idx = blockIdx.x * 256 + threadIdx.x;      // b*65536 + chunk*1024 + ch
    int ch = idx & (H_DIM - 1);
    int chunk = (idx >> 10) & (NCHUNK - 1);
    int b = idx >> 16;
    int t0 = chunk * CHUNK;
    size_t base = ((size_t)b * T_DIM + t0) * H_DIM + ch;
    const float* ii = is_init + (size_t)b * T_DIM + t0;
    float A = 1.f, Bv = 0.f;
    int rf = 0;
    for (int i = 0; i < CHUNK; i++) {
        uint32_t d = Sab[base + (size_t)i * H_DIM];
        float a = b2f((unsigned short)(d & 0xffffu));
        float bb = b2f((unsigned short)(d >> 16));
        bool rst = ii[i] > 0.f;
        A = rst ? a : a * A;
        Bv = rst ? bb : fmaf(a, Bv, bb);
        rf |= (int)rst;
    }
    size_t o = ((size_t)b * NCHUNK + chunk) * H_DIM + ch;
    CA[o] = A;
    CB[o] = Bv;
    if (ch == 0) CR[b * NCHUNK + chunk] = (float)rf;
}

__global__ void scan_tops(const float* __restrict__ CA, const float* __restrict__ CB,
                          const float* __restrict__ CR,
                          float* __restrict__ PA, float* __restrict__ PB) {
    int idx = blockIdx.x * blockDim.x + threadIdx.x;   // 0 .. B*H-1
    if (idx >= B_DIM * H_DIM) return;
    int ch = idx & (H_DIM - 1);
    int b = idx >> 10;
    float A = 1.f, Bv = 0.f;
    for (int c = 0; c < NCHUNK; c++) {
        size_t o = ((size_t)b * NCHUNK + c) * H_DIM + ch;
        PA[o] = A;            // exclusive prefix
        PB[o] = Bv;
        float a = CA[o], bb = CB[o];
        bool rst = CR[b * NCHUNK + c] > 0.f;
        float nA = rst ? a : a * A;
        float nB = rst ? bb : fmaf(a, Bv, bb);
        A = nA; Bv = nB;
    }
}

__global__ __launch_bounds__(256) void scan_apply(
    const uint32_t* __restrict__ Sab, const float* __restrict__ is_init,
    const float* __restrict__ PA, const float* __restrict__ PB,
    const float* __restrict__ h0,
    unsigned short* __restrict__ hb, float* __restrict__ hn) {
    int idx = blockIdx.x * 256 + threadIdx.x;
    int ch = idx & (H_DIM - 1);
    int chunk = (idx >> 10) & (NCHUNK - 1);
    int b = idx >> 16;
    int t0 = chunk * CHUNK;
    size_t base = ((size_t)b * T_DIM + t0) * H_DIM + ch;
    const float* ii = is_init + (size_t)b * T_DIM + t0;
    size_t po = ((size_t)b * NCHUNK + chunk) * H_DIM + ch;
    float A = PA[po], Bv = PB[po];
    float h0v = h0[b * H_DIM + ch];
    float h = 0.f;
    for (int i = 0; i < CHUNK; i++) {
        uint32_t d = Sab[base + (size_t)i * H_DIM];
        float a = b2f((unsigned short)(d & 0xffffu));
        float bb = b2f((unsigned short)(d >> 16));
        bool rst = ii[i] > 0.f;
        A = rst ? a : a * A;
        Bv = rst ? bb : fmaf(a, Bv, bb);
        h = fmaf(A, h0v, Bv);
        hb[base + (size_t)i * H_DIM] = f2b(h);
    }
    if (chunk == NCHUNK - 1) hn[b * H_DIM + ch] = h;
}

// ---------------- launcher ----------------

extern "C" void kernel_launch(void* const* d_in, const int* in_sizes, int n_in,
                              void* d_out, int out_size, void* d_ws, size_t ws_size,
                              hipStream_t stream) {
    const float* x       = (const float*)d_in[0];
    const float* W_hg    = (const float*)d_in[1];
    const float* W_out   = (const float*)d_in[2];
    const float* is_init = (const float*)d_in[3];
    const float* h0      = (const float*)d_in[4];
    float* out = (float*)d_out;
    float* hn  = out + (size_t)M_DIM * H_DIM;

    char* ws = (char*)d_ws;
    size_t off = 0;
    auto alloc = [&](size_t bytes) {
        void* p = ws + off;
        off += (bytes + 255) & ~(size_t)255;
        return p;
    };
    unsigned short* xb  = (unsigned short*)alloc((size_t)M_DIM * K_DIM * 2); // reused as hb
    unsigned short* Wp  = (unsigned short*)alloc((size_t)2 * H_DIM * K_DIM * 2);
    unsigned short* Wob = (unsigned short*)alloc((size_t)H_DIM * K_DIM * 2);
    uint32_t* Sab = (uint32_t*)alloc((size_t)M_DIM * H_DIM * 4);
    float* CA = (float*)alloc((size_t)B_DIM * NCHUNK * H_DIM * 4);
    float* CB = (float*)alloc((size_t)B_DIM * NCHUNK * H_DIM * 4);
    float* CR = (float*)alloc((size_t)B_DIM * NCHUNK * 4);
    float* PA = (float*)alloc((size_t)B_DIM * NCHUNK * H_DIM * 4);
    float* PB = (float*)alloc((size_t)B_DIM * NCHUNK * H_DIM * 4);
    unsigned short* hb = xb;   // alias: x_bf16 dead after GEMM1

    // 1) conversions
    cvt_f32_bf16<<<2048, 256, 0, stream>>>(x, xb, M_DIM * K_DIM / 4);
    prep_whg<<<(2 * H_DIM * K_DIM / 4 + 255) / 256, 256, 0, stream>>>(W_hg, Wp);
    cvt_f32_bf16<<<1024, 256, 0, stream>>>(W_out, Wob, H_DIM * K_DIM / 4);

    // 2) GEMM1 with fused gating epilogue (N = 2048 interleaved cols)
    gemm256<1><<<dim3(2048 / 256, M_DIM / 256), 512, 0, stream>>>(
        xb, Wp, nullptr, Sab, 2048);

    // 3) 3-pass chunked scan over time (packed coefficients)
    scan_chunks<<<(B_DIM * NCHUNK * H_DIM) / 256, 256, 0, stream>>>(
        Sab, is_init, CA, CB, CR);
    scan_tops<<<(B_DIM * H_DIM + 255) / 256, 256, 0, stream>>>(CA, CB, CR, PA, PB);
    scan_apply<<<(B_DIM * NCHUNK * H_DIM) / 256, 256, 0, stream>>>(
        Sab, is_init, PA, PB, h0, hb, hn);

    // 4) GEMM2: out = h @ W_out^T
    gemm256<0><<<dim3(1024 / 256, M_DIM / 256), 512, 0, stream>>>(
        hb, Wob, out, nullptr, 1024);
}

// Round 11
// 354.647 us; speedup vs baseline: 1.3858x; 1.2894x over previous
//
#include <hip/hip_runtime.h>
#include <stdint.h>

#define B_DIM 8
#define T_DIM 4096
#define K_DIM 1024
#define H_DIM 1024
#define M_DIM (B_DIM * T_DIM)      // 32768
#define CHUNK 64
#define NCHUNK (T_DIM / CHUNK)     // 64

typedef __attribute__((ext_vector_type(8))) short s16x8;
typedef __attribute__((ext_vector_type(4))) float f32x4;

__device__ __forceinline__ unsigned short f2b(float f) {
    union { float f; uint32_t u; } c; c.f = f;
    uint32_t r = (c.u + 0x7fffu + ((c.u >> 16) & 1u)) >> 16;
    return (unsigned short)r;
}
__device__ __forceinline__ float b2f(unsigned short u) {
    union { uint32_t u; float f; } c; c.u = ((uint32_t)u) << 16;
    return c.f;
}

// async global->LDS, 16B per lane. LDS dest = wave-uniform base + lane*16.
__device__ __forceinline__ void gload_lds16(const unsigned short* g,
                                            unsigned short* l) {
    __builtin_amdgcn_global_load_lds(
        (__attribute__((address_space(1))) void*)g,
        (__attribute__((address_space(3))) void*)l, 16, 0, 0);
}

__device__ __forceinline__ void bar() {
    asm volatile("s_barrier" ::: "memory");
}

// ---------------- conversion kernels ----------------

__global__ void cvt_f32_bf16(const float* __restrict__ src,
                             unsigned short* __restrict__ dst, int n4) {
    int stride = gridDim.x * blockDim.x;
    for (int i = blockIdx.x * blockDim.x + threadIdx.x; i < n4; i += stride) {
        float4 v = ((const float4*)src)[i];
        ushort4 o;
        o.x = f2b(v.x); o.y = f2b(v.y); o.z = f2b(v.z); o.w = f2b(v.w);
        ((ushort4*)dst)[i] = o;
    }
}

// W'[2c+0][k] = W_hg[c][k] (hidden row), W'[2c+1][k] = W_hg[H+c][k] (gate row)
__global__ void prep_whg(const float* __restrict__ W,
                         unsigned short* __restrict__ Wp) {
    int i = blockIdx.x * blockDim.x + threadIdx.x;
    int total = 2 * H_DIM * K_DIM / 4;
    if (i >= total) return;
    int e = i * 4;
    int n = e >> 10;          // K = 1024
    int k = e & 1023;
    int src = (n & 1) ? (H_DIM + (n >> 1)) : (n >> 1);
    float4 v = *(const float4*)&W[(size_t)src * K_DIM + k];
    ushort4 o;
    o.x = f2b(v.x); o.y = f2b(v.y); o.z = f2b(v.z); o.w = f2b(v.w);
    *(ushort4*)&Wp[(size_t)n * K_DIM + k] = o;
}

// ---------------- 256x256 4-phase bf16 MFMA GEMM (R4 schedule, verbatim) ----
// Staging spread 3/3/2 over phases 1-3; validation vmcnt(0) in phase 4.
// dbuf LDS 128KB, XOR slot-swizzle via pre-swizzled global source.
// EPI==0: f32 store. EPI==1: fused minGRU gating epilogue -> packed u32
//         Sab[row][ch] = {lo: bf16(1-g), hi: bf16(g*hidden)}.

template <int EPI>
__global__ __launch_bounds__(512, 2) void gemm256(
    const unsigned short* __restrict__ A,
    const unsigned short* __restrict__ Bm,
    float* __restrict__ C,
    uint32_t* __restrict__ Sab,
    int N) {
    __shared__ unsigned short As[2][256 * 64];
    __shared__ unsigned short Bs[2][256 * 64];
    const int K = K_DIM;
    const int KT = K / 64;

    // T1: bijective XCD swizzle (nwg % 8 == 0 for both GEMMs here)
    const int gx = gridDim.x;
    const int nwg = gx * gridDim.y;
    const int orig = blockIdx.y * gx + blockIdx.x;
    const int cpx = nwg >> 3;
    const int wg = (orig & 7) * cpx + (orig >> 3);
    const int m0 = (wg / gx) * 256;
    const int n0 = (wg % gx) * 256;

    const int t = threadIdx.x;
    const int lane = t & 63;
    const int w = t >> 6;               // 0..7
    const int wm = w >> 2, wn = w & 3;  // 2 x 4 wave grid

    const int lrow = lane >> 3;
    const int lslot = (lane & 7) ^ lrow;

    const int l15 = lane & 15;
    const int rq = lane >> 4;          // 0..3
    const int rx = l15 & 7;

    f32x4 acc[8][4];
#pragma unroll
    for (int m = 0; m < 8; m++)
#pragma unroll
        for (int n = 0; n < 4; n++) acc[m][n] = (f32x4){0.f, 0.f, 0.f, 0.f};

    auto stageA = [&](int kt, int buf, int j) {
        const int seg = j * 8 + w;
        const int row = seg * 8 + lrow;
        gload_lds16(&A[(size_t)(m0 + row) * K + kt * 64 + lslot * 8],
                    &As[buf][seg * 512]);
    };
    auto stageB = [&](int kt, int buf, int j) {
        const int seg = j * 8 + w;
        const int row = seg * 8 + lrow;
        gload_lds16(&Bm[(size_t)(n0 + row) * K + kt * 64 + lslot * 8],
                    &Bs[buf][seg * 512]);
    };

    s16x8 af[4], bf[4];

#define LDA(buf, mi, ks) \
    (*(const s16x8*)&As[buf][(wm * 128 + (mi) * 16 + l15) * 64 + (((rq + (ks) * 4) ^ rx) * 8)])
#define LDB(buf, ni, ks) \
    (*(const s16x8*)&Bs[buf][(wn * 64 + (ni) * 16 + l15) * 64 + (((rq + (ks) * 4) ^ rx) * 8)])

#define MFMA16(MB)                                                          \
    __builtin_amdgcn_s_setprio(1);                                          \
    _Pragma("unroll") for (int m = 0; m < 4; m++)                           \
        _Pragma("unroll") for (int n = 0; n < 4; n++)                       \
            acc[MB + m][n] = __builtin_amdgcn_mfma_f32_16x16x32_bf16(       \
                af[m], bf[n], acc[MB + m][n], 0, 0, 0);                     \
    __builtin_amdgcn_s_setprio(0);

    // prologue: stage tile 0 fully, validate
    {
#pragma unroll
        for (int j = 0; j < 4; j++) stageA(0, 0, j);
#pragma unroll
        for (int j = 0; j < 4; j++) stageB(0, 0, j);
        asm volatile("s_waitcnt vmcnt(0)" ::: "memory");
        bar();
    }

    for (int kt = 0; kt < KT; ++kt) {
        const int buf = kt & 1;
        const int nb = buf ^ 1;
        const bool nx = (kt + 1 < KT);
        // ---- phase 1
#pragma unroll
        for (int m = 0; m < 4; m++) af[m] = LDA(buf, m, 0);
#pragma unroll
        for (int n = 0; n < 4; n++) bf[n] = LDB(buf, n, 0);
        if (nx) { stageA(kt + 1, nb, 0); stageA(kt + 1, nb, 1); stageB(kt + 1, nb, 0); }
        bar();
        MFMA16(0);
        bar();
        // ---- phase 2
#pragma unroll
        for (int m = 0; m < 4; m++) af[m] = LDA(buf, m + 4, 0);
        if (nx) { stageA(kt + 1, nb, 2); stageA(kt + 1, nb, 3); stageB(kt + 1, nb, 1); }
        bar();
        MFMA16(4);
        bar();
        // ---- phase 3
#pragma unroll
        for (int m = 0; m < 4; m++) af[m] = LDA(buf, m, 1);
#pragma unroll
        for (int n = 0; n < 4; n++) bf[n] = LDB(buf, n, 1);
        if (nx) { stageB(kt + 1, nb, 2); stageB(kt + 1, nb, 3); }
        bar();
        MFMA16(0);
        bar();
        // ---- phase 4: pipelined validation of tile kt+1
#pragma unroll
        for (int m = 0; m < 4; m++) af[m] = LDA(buf, m + 4, 1);
        asm volatile("s_waitcnt vmcnt(0)" ::: "memory");
        bar();
        MFMA16(4);
        bar();
    }

    // ---- epilogue
    const int lr4 = rq * 4;
#pragma unroll
    for (int m = 0; m < 8; m++) {
#pragma unroll
        for (int n = 0; n < 4; n++) {
#pragma unroll
            for (int r = 0; r < 4; r++) {
                const int row = m0 + wm * 128 + m * 16 + lr4 + r;
                const int col = n0 + wn * 64 + n * 16 + l15;
                float v = acc[m][n][r];
                if (EPI == 0) {
                    C[(size_t)row * N + col] = v;
                } else {
                    float o = __shfl_xor(v, 1);   // all lanes execute
                    if ((lane & 1) == 0) {
                        // even lane: v = hidden, o = gate logit -> pack both
                        float g = 1.f / (1.f + __expf(-o));
                        uint32_t pk = (uint32_t)f2b(1.f - g) |
                                      ((uint32_t)f2b(g * v) << 16);
                        Sab[(size_t)row * H_DIM + (col >> 1)] = pk;
                    }
                }
            }
        }
    }
#undef LDA
#undef LDB
#undef MFMA16
}

// ---------------- chunked scan (3-pass, packed coefficients) ----------------
// Element combine (matches reference): carry (A,Bv); element (a,b,r):
//   r>0 : (A,Bv) = (a, b)      else : (A,Bv) = (a*A, a*Bv + b)

__global__ __launch_bounds__(256) void scan_chunks(
    const uint32_t* __restrict__ Sab, const float* __restrict__ is_init,
    float* __restrict__ CA, float* __restrict__ CB, float* __restrict__ CR) {
    int idx = blockIdx.x * 256 + threadIdx.x;      // b*65536 + chunk*1024 + ch
    int ch = idx & (H_DIM - 1);
    int chunk = (idx >> 10) & (NCHUNK - 1);
    int b = idx >> 16;
    int t0 = chunk * CHUNK;
    size_t base = ((size_t)b * T_DIM + t0) * H_DIM + ch;
    const float* ii = is_init + (size_t)b * T_DIM + t0;
    float A = 1.f, Bv = 0.f;
    int rf = 0;
    for (int i = 0; i < CHUNK; i++) {
        uint32_t d = Sab[base + (size_t)i * H_DIM];
        float a = b2f((unsigned short)(d & 0xffffu));
        float bb = b2f((unsigned short)(d >> 16));
        bool rst = ii[i] > 0.f;
        A = rst ? a : a * A;
        Bv = rst ? bb : fmaf(a, Bv, bb);
        rf |= (int)rst;
    }
    size_t o = ((size_t)b * NCHUNK + chunk) * H_DIM + ch;
    CA[o] = A;
    CB[o] = Bv;
    if (ch == 0) CR[b * NCHUNK + chunk] = (float)rf;
}

__global__ void scan_tops(const float* __restrict__ CA, const float* __restrict__ CB,
                          const float* __restrict__ CR,
                          float* __restrict__ PA, float* __restrict__ PB) {
    int idx = blockIdx.x * blockDim.x + threadIdx.x;   // 0 .. B*H-1
    if (idx >= B_DIM * H_DIM) return;
    int ch = idx & (H_DIM - 1);
    int b = idx >> 10;
    float A = 1.f, Bv = 0.f;
    for (int c = 0; c < NCHUNK; c++) {
        size_t o = ((size_t)b * NCHUNK + c) * H_DIM + ch;
        PA[o] = A;            // exclusive prefix
        PB[o] = Bv;
        float a = CA[o], bb = CB[o];
        bool rst = CR[b * NCHUNK + c] > 0.f;
        float nA = rst ? a : a * A;
        float nB = rst ? bb : fmaf(a, Bv, bb);
        A = nA; Bv = nB;
    }
}

__global__ __launch_bounds__(256) void scan_apply(
    const uint32_t* __restrict__ Sab, const float* __restrict__ is_init,
    const float* __restrict__ PA, const float* __restrict__ PB,
    const float* __restrict__ h0,
    unsigned short* __restrict__ hb, float* __restrict__ hn) {
    int idx = blockIdx.x * 256 + threadIdx.x;
    int ch = idx & (H_DIM - 1);
    int chunk = (idx >> 10) & (NCHUNK - 1);
    int b = idx >> 16;
    int t0 = chunk * CHUNK;
    size_t base = ((size_t)b * T_DIM + t0) * H_DIM + ch;
    const float* ii = is_init + (size_t)b * T_DIM + t0;
    size_t po = ((size_t)b * NCHUNK + chunk) * H_DIM + ch;
    float A = PA[po], Bv = PB[po];
    float h0v = h0[b * H_DIM + ch];
    float h = 0.f;
    for (int i = 0; i < CHUNK; i++) {
        uint32_t d = Sab[base + (size_t)i * H_DIM];
        float a = b2f((unsigned short)(d & 0xffffu));
        float bb = b2f((unsigned short)(d >> 16));
        bool rst = ii[i] > 0.f;
        A = rst ? a : a * A;
        Bv = rst ? bb : fmaf(a, Bv, bb);
        h = fmaf(A, h0v, Bv);
        hb[base + (size_t)i * H_DIM] = f2b(h);
    }
    if (chunk == NCHUNK - 1) hn[b * H_DIM + ch] = h;
}

// ---------------- launcher ----------------

extern "C" void kernel_launch(void* const* d_in, const int* in_sizes, int n_in,
                              void* d_out, int out_size, void* d_ws, size_t ws_size,
                              hipStream_t stream) {
    const float* x       = (const float*)d_in[0];
    const float* W_hg    = (const float*)d_in[1];
    const float* W_out   = (const float*)d_in[2];
    const float* is_init = (const float*)d_in[3];
    const float* h0      = (const float*)d_in[4];
    float* out = (float*)d_out;
    float* hn  = out + (size_t)M_DIM * H_DIM;

    char* ws = (char*)d_ws;
    size_t off = 0;
    auto alloc = [&](size_t bytes) {
        void* p = ws + off;
        off += (bytes + 255) & ~(size_t)255;
        return p;
    };
    unsigned short* xb  = (unsigned short*)alloc((size_t)M_DIM * K_DIM * 2); // reused as hb
    unsigned short* Wp  = (unsigned short*)alloc((size_t)2 * H_DIM * K_DIM * 2);
    unsigned short* Wob = (unsigned short*)alloc((size_t)H_DIM * K_DIM * 2);
    uint32_t* Sab = (uint32_t*)alloc((size_t)M_DIM * H_DIM * 4);
    float* CA = (float*)alloc((size_t)B_DIM * NCHUNK * H_DIM * 4);
    float* CB = (float*)alloc((size_t)B_DIM * NCHUNK * H_DIM * 4);
    float* CR = (float*)alloc((size_t)B_DIM * NCHUNK * 4);
    float* PA = (float*)alloc((size_t)B_DIM * NCHUNK * H_DIM * 4);
    float* PB = (float*)alloc((size_t)B_DIM * NCHUNK * H_DIM * 4);
    unsigned short* hb = xb;   // alias: x_bf16 dead after GEMM1

    // 1) conversions
    cvt_f32_bf16<<<2048, 256, 0, stream>>>(x, xb, M_DIM * K_DIM / 4);
    prep_whg<<<(2 * H_DIM * K_DIM / 4 + 255) / 256, 256, 0, stream>>>(W_hg, Wp);
    cvt_f32_bf16<<<1024, 256, 0, stream>>>(W_out, Wob, H_DIM * K_DIM / 4);

    // 2) GEMM1 with fused gating epilogue (N = 2048 interleaved cols)
    gemm256<1><<<dim3(2048 / 256, M_DIM / 256), 512, 0, stream>>>(
        xb, Wp, nullptr, Sab, 2048);

    // 3) 3-pass chunked scan over time (packed coefficients)
    scan_chunks<<<(B_DIM * NCHUNK * H_DIM) / 256, 256, 0, stream>>>(
        Sab, is_init, CA, CB, CR);
    scan_tops<<<(B_DIM * H_DIM + 255) / 256, 256, 0, stream>>>(CA, CB, CR, PA, PB);
    scan_apply<<<(B_DIM * NCHUNK * H_DIM) / 256, 256, 0, stream>>>(
        Sab, is_init, PA, PB, h0, hb, hn);

    // 4) GEMM2: out = h @ W_out^T
    gemm256<0><<<dim3(1024 / 256, M_DIM / 256), 512, 0, stream>>>(
        hb, Wob, out, nullptr, 1024);
}